// Round 7
// baseline (486.878 us; speedup 1.0000x reference)
//
#include <hip/hip_runtime.h>

// HMM forward scan, one workgroup per unit u. U=256, N=64, S=4, B=64, T=1024.
// Wave w owns batches [16w,16w+16); lane (q=lane>>4,l=lane&15) owns batch
// b=16w+l and the 16 states j = sig(jt, 4q+r).
//
// R15: MINIMAL MFMA COUNT + GAP-FILL INTERLEAVE.
// Evidence R8-R14: period ~= N_mfma * ~55cy + unhidden-VALU; the ~35cy/MFMA
// issue stall of a single wave (1 wave/SIMD, fixed) is fillable only if
// independent VALU work sits BETWEEN the MFMAs in issue order. All prior
// rounds kept a clean V-phase/M-phase split -> gaps empty (R13) or VALU
// un-hidden (R12). R14's barrier-paired TLP regressed (lockstep).
// This round:
//  - 8 MFMAs/step (the R-matvec floor: 4 output tiles x 2 K-halves,
//    unchained per R13).
//  - E on VALU (64 fma; depends only on prefetched x) computed for step
//    t+1 INSIDE step t's M-phase, textually interleaved between MFMA
//    pairs; sched_group_barrier pins the MFMA2/VALUn alternation.
//  - ss via in-lane adds + 3 shfl_xor issued in the gaps, consumed lag-1
//    (R10's proven capture flow).
//  - octet pow2 rescale folded into E's input (xs = x*fcur at slot 7 for
//    next octet's slot 0) -> no Rv-rescale pass, no slot-0 special case.
//    fcur derived early at consume(5) (slot 6) so slot 7 can use it.
// Unnormalized recursion + exact pow2 octet rescale + once-per-32 flush
// unchanged from R10/R13 (proven).

#define U_ 256
#define N_ 64
#define S_ 4
#define B_ 64
#define T_ 1024
#define ROWP 72
#define LN2F 0.69314718055994530942f

typedef __attribute__((ext_vector_type(8))) __bf16 bf16x8;
typedef __attribute__((ext_vector_type(4))) float floatx4;

#define SGB __builtin_amdgcn_sched_group_barrier

__device__ __forceinline__ int sig(int jt, int m) {
    return 32 * (jt >> 1) + 4 * (jt & 1) + 8 * (m >> 2) + (m & 3);
}

__launch_bounds__(256, 1)
__global__ void hmm_fwd_kernel(const float* __restrict__ xg,     // [B][T][S]
                               const float* __restrict__ trans,  // [U][N][N]
                               const float* __restrict__ emis,   // [U][N][S]
                               const float* __restrict__ initk,  // [U][N]
                               float* __restrict__ out)          // [B][T][U]
{
    __shared__ __bf16 AT[N_ * ROWP];
    __shared__ float BemS[N_][S_];
    __shared__ float IS[N_];

    const int bid = blockIdx.x;
    const int u = ((bid & 7) << 5) | (bid >> 3);   // XCD-aware u swizzle
    const int tid = threadIdx.x;
    const int lane = tid & 63;
    const int w = tid >> 6;
    const int q = lane >> 4;
    const int l = lane & 15;

    // ---------------- prologue: softmaxes (one-time) ----------------
    if (tid < 64) {
        const float* rowp = trans + (u * N_ + tid) * N_;
        float v[N_];
        #pragma unroll
        for (int k = 0; k < 16; ++k) {
            floatx4 t4 = *(const floatx4*)(rowp + 4 * k);
            v[4*k] = t4.x; v[4*k+1] = t4.y; v[4*k+2] = t4.z; v[4*k+3] = t4.w;
        }
        float m = v[0];
        #pragma unroll
        for (int j = 1; j < N_; ++j) m = fmaxf(m, v[j]);
        float s = 0.f;
        #pragma unroll
        for (int j = 0; j < N_; ++j) { v[j] = __expf(v[j] - m); s += v[j]; }
        float inv = 1.0f / s;
        #pragma unroll
        for (int j = 0; j < N_; ++j) AT[j * ROWP + tid] = (__bf16)(v[j] * inv);
    } else if (tid < 128) {
        int n = tid - 64;
        floatx4 e4 = *(const floatx4*)(emis + (u * N_ + n) * S_);
        float m = fmaxf(fmaxf(e4.x, e4.y), fmaxf(e4.z, e4.w));
        float a = __expf(e4.x - m), b2 = __expf(e4.y - m);
        float c = __expf(e4.z - m), d = __expf(e4.w - m);
        float inv = 1.0f / (a + b2 + c + d);
        BemS[n][0] = a*inv; BemS[n][1] = b2*inv; BemS[n][2] = c*inv; BemS[n][3] = d*inv;
    } else if (tid < 192) {
        int j = tid - 128;
        float v = initk[u * N_ + j];
        float m = v;
        #pragma unroll
        for (int s = 1; s < 64; s <<= 1) m = fmaxf(m, __shfl_xor(m, s, 64));
        float e = __expf(v - m);
        float ssum = e;
        #pragma unroll
        for (int s = 1; s < 64; s <<= 1) ssum += __shfl_xor(ssum, s, 64);
        IS[j] = e / ssum;
    }
    __syncthreads();

    // ------------- persistent register state -------------
    bf16x8 afrag[4][2];
    #pragma unroll
    for (int jt = 0; jt < 4; ++jt)
        #pragma unroll
        for (int kt = 0; kt < 2; ++kt)
            afrag[jt][kt] = *(const bf16x8*)&AT[sig(jt, l) * ROWP + 32*kt + 8*q];

    // f32 emission coefficients, one floatx4 per owned state (VALU E)
    floatx4 cBem[4][4];
    #pragma unroll
    for (int jt = 0; jt < 4; ++jt)
        #pragma unroll
        for (int r = 0; r < 4; ++r)
            cBem[jt][r] = *(const floatx4*)&BemS[sig(jt, 4*q + r)][0];

    // Rv(t) = P0+P1 combined lag-1 on VALU (R13, unchained)
    floatx4 P0[4], P1[4];
    #pragma unroll
    for (int jt = 0; jt < 4; ++jt)
        #pragma unroll
        for (int r = 0; r < 4; ++r) {
            P0[jt][r] = IS[sig(jt, 4*q + r)];
            P1[jt][r] = 0.f;
        }

    __asm__ volatile("" ::: "memory");   // pin LDS-sourced state in VGPRs

    const int b = 16*w + l;
    const float* xin = xg + b * (T_ * S_);
    float* llout = out + (size_t)b * T_ * U_ + u;

    const floatx4 z = {0.f, 0.f, 0.f, 0.f};

    auto dot4 = [](const floatx4& cb, const floatx4& x4) {
        return fmaf(cb.x, x4.x, fmaf(cb.y, x4.y, fmaf(cb.z, x4.z, cb.w * x4.w)));
    };

    // E ping-pong buffers (static names, parity by slot -> no runtime index)
    floatx4 EvA[4], EvB[4];
    {
        floatx4 x0 = *(const floatx4*)xin;
        #pragma unroll
        for (int jt = 0; jt < 4; ++jt)
            #pragma unroll
            for (int r = 0; r < 4; ++r)
                EvA[jt][r] = dot4(cBem[jt][r], x0);
    }

    floatx4 xvA[4], xvB[4];
    #pragma unroll
    for (int i = 0; i < 4; ++i)
        xvA[i] = *(const floatx4*)(xin + (1 + i) * S_);   // x_1..x_4 raw

    float hist[8];
    float ssf = 1.0f;
    float fcur = 1.0f;
    float pp0 = 0.f, pa16 = 0.f, pa32 = 0.f, pa48 = 0.f;
    float Cacc = 0.f;
    float offacc = 0.f, sumk = 0.f;

    // consume step (slot kprev)'s shfl results: raw ss capture; derive
    // fcur early (at kprev==5, i.e. during slot 6) so slot 7's E can fold it.
    auto consume = [&](int kprev, bool o) {
        float ss = (pp0 + pa16) + (pa32 + pa48);
        hist[kprev] = o ? ss : hist[kprev];
        if (kprev == 5) {
            ssf = ss;
            unsigned eb = (__float_as_uint(ss) >> 23) & 255u;
            fcur = __uint_as_float((254u - eb) << 23);
        }
    };

    // one HMM step. xnx = raw x_{t+1}; Ein = E_t; Eout = E_{t+1};
    // fs = 1 except slot 7 (octet rescale folded into next slot-0's E).
    auto step = [&](const floatx4& xnx, int slot, bool own, bool ownP,
                    const floatx4* Ein, floatx4* Eout, float fs) {
        // ---- serial V tail ----
        floatx4 gv[4];
        #pragma unroll
        for (int jt = 0; jt < 4; ++jt) {
            floatx4 Rv = P0[jt] + P1[jt];
            gv[jt] = Ein[jt] * Rv;
        }
        bf16x8 bf0, bf1;
        #pragma unroll
        for (int p = 0; p < 4; ++p) {
            bf0[p]     = (__bf16)gv[0][p];
            bf0[4 + p] = (__bf16)gv[1][p];
            bf1[p]     = (__bf16)gv[2][p];
            bf1[4 + p] = (__bf16)gv[3][p];
        }

        // ---- M phase: 8 MFMAs with gap-fill interleave ----
        P0[0] = __builtin_amdgcn_mfma_f32_16x16x32_bf16(afrag[0][0], bf0, z, 0, 0, 0);
        P1[0] = __builtin_amdgcn_mfma_f32_16x16x32_bf16(afrag[0][1], bf1, z, 0, 0, 0);

        if (slot == 0) consume(7, ownP); else consume(slot - 1, own);

        P0[1] = __builtin_amdgcn_mfma_f32_16x16x32_bf16(afrag[1][0], bf0, z, 0, 0, 0);
        P1[1] = __builtin_amdgcn_mfma_f32_16x16x32_bf16(afrag[1][1], bf1, z, 0, 0, 0);

        floatx4 xs = xnx * fs;
        #pragma unroll
        for (int jt = 0; jt < 2; ++jt)
            #pragma unroll
            for (int r = 0; r < 4; ++r)
                Eout[jt][r] = dot4(cBem[jt][r], xs);

        P0[2] = __builtin_amdgcn_mfma_f32_16x16x32_bf16(afrag[2][0], bf0, z, 0, 0, 0);
        P1[2] = __builtin_amdgcn_mfma_f32_16x16x32_bf16(afrag[2][1], bf1, z, 0, 0, 0);

        #pragma unroll
        for (int jt = 2; jt < 4; ++jt)
            #pragma unroll
            for (int r = 0; r < 4; ++r)
                Eout[jt][r] = dot4(cBem[jt][r], xs);

        P0[3] = __builtin_amdgcn_mfma_f32_16x16x32_bf16(afrag[3][0], bf0, z, 0, 0, 0);
        P1[3] = __builtin_amdgcn_mfma_f32_16x16x32_bf16(afrag[3][1], bf1, z, 0, 0, 0);

        // ss reduce issued last, consumed lag-1 (hides in gaps)
        floatx4 s4 = (gv[0] + gv[1]) + (gv[2] + gv[3]);
        pp0  = (s4.x + s4.y) + (s4.z + s4.w);
        pa16 = __shfl_xor(pp0, 16, 64);
        pa32 = __shfl_xor(pp0, 32, 64);
        pa48 = __shfl_xor(pp0, 48, 64);

        // pin the interleave: V tail, then MFMA2/VALUn alternation
        SGB(0x2, 40, 0);               // V tail: Rv add, gv mul, packs
        SGB(0x8, 2, 0); SGB(0x2, 8, 0);    // pair0 | consume
        SGB(0x8, 2, 0); SGB(0x2, 32, 0);   // pair1 | xs + E jt0,1
        SGB(0x8, 2, 0); SGB(0x2, 32, 0);   // pair2 | E jt2,3
        SGB(0x8, 2, 0); SGB(0x2, 12, 0);   // pair3 | ss sums
    };

    // ---------------- T-loop: one octet per iteration ----------------
    #pragma unroll 1
    for (int tb = 0; tb < T_; tb += 8) {
        const int oct = (tb >> 3) & 3;
        const bool own  = (q == oct);
        const bool ownP = (q == ((oct + 3) & 3));

        #pragma unroll
        for (int i = 0; i < 4; ++i) {
            int ti = tb + 5 + i; ti = (ti < T_) ? ti : T_ - 1;
            xvB[i] = *(const floatx4*)(xin + ti * S_);
        }

        step(xvA[0], 0, own, ownP, EvA, EvB, 1.0f);
        step(xvA[1], 1, own, ownP, EvB, EvA, 1.0f);
        step(xvA[2], 2, own, ownP, EvA, EvB, 1.0f);
        step(xvA[3], 3, own, ownP, EvB, EvA, 1.0f);

        #pragma unroll
        for (int i = 0; i < 4; ++i) {
            int ti = tb + 9 + i; ti = (ti < T_) ? ti : T_ - 1;
            xvA[i] = *(const floatx4*)(xin + ti * S_);
        }

        step(xvB[0], 4, own, ownP, EvA, EvB, 1.0f);
        step(xvB[1], 5, own, ownP, EvB, EvA, 1.0f);
        step(xvB[2], 6, own, ownP, EvA, EvB, 1.0f);
        step(xvB[3], 7, own, ownP, EvB, EvA, fcur);   // fold octet rescale

        if (oct == 3) consume(7, own);   // pre-flush tail (once per 32)

        // octet boundary: kf accounting from ssraw_{slot5} (fcur already
        // derived at consume(5) and folded into next slot-0's E).
        {
            unsigned eb = (__float_as_uint(ssf) >> 23) & 255u;
            float kf = (float)((int)eb - 127);
            offacc += (q > oct) ? kf : 0.f;   // octets before lane q's octet
            sumk   += kf;
        }

        // ---------------- flush: ll_t = log(ssraw_t) + correction -------
        if (oct == 3) {
            float base = Cacc + LN2F * offacc;
            float* fp = llout + (size_t)(tb - 24 + 8 * q) * U_;
            #pragma unroll
            for (int k = 0; k < 8; ++k)
                fp[(size_t)k * U_] = __logf(hist[k]) + base;
            Cacc += LN2F * sumk;
            offacc = 0.f; sumk = 0.f;
        }
    }
}

extern "C" void kernel_launch(void* const* d_in, const int* in_sizes, int n_in,
                              void* d_out, int out_size, void* d_ws, size_t ws_size,
                              hipStream_t stream) {
    const float* xg    = (const float*)d_in[0];
    const float* trans = (const float*)d_in[1];
    const float* emis  = (const float*)d_in[2];
    const float* initk = (const float*)d_in[3];
    float* out = (float*)d_out;
    hipLaunchKernelGGL(hmm_fwd_kernel, dim3(U_), dim3(256), 0, stream,
                       xg, trans, emis, initk, out);
}

// Round 8
// 472.647 us; speedup vs baseline: 1.0301x; 1.0301x over previous
//
#include <hip/hip_runtime.h>

// HMM forward scan. U=256, N=64, S=4, B=64, T=1024.
// R16: 2 INDEPENDENT WAVES PER SIMD via batch-split (no exchange).
// Evidence: R13 (1 wave/SIMD) has MfmaUtil 33% with per-MFMA pipe
// occupancy already at the saturated 17.5-19.4cy -> the idle 66% is the
// single in-order wave alternating V-phase/M-phase. R14 proved 2
// waves/SIMD feed the pipe at full rate (busy 276cy ~= demand 310cy) but
// lost ~640cy/step to its barrier+exchange lockstep. Fix: make the two
// waves per SIMD INDEPENDENT - split each 16-batch group into two
// 8-batch waves. 256 blocks x 512 threads = 2048 waves = 8/CU = 2/SIMD,
// zero main-loop sync. MFMA shapes unchanged; B-operand cols 8-15 are
// structurally zero (lanes l>=8 hold R=0, so their gv packs are 0);
// stores guarded l<8.
// Per wave: 12 MFMAs = R x8 (unchained half-K accumulators, R13) +
// E x4 (MFMA E); ss via in-lane adds + 3 shfl_xor (R10's proven flow;
// DS latency hides under the partner wave's MFMAs).
// Unnormalized recursion + exact pow2 octet rescale + once-per-32 flush
// unchanged from R10/R13 (proven).

#define U_ 256
#define N_ 64
#define S_ 4
#define B_ 64
#define T_ 1024
#define ROWP 72
#define LN2F 0.69314718055994530942f

typedef __attribute__((ext_vector_type(8))) __bf16 bf16x8;
typedef __attribute__((ext_vector_type(4))) float floatx4;

__device__ __forceinline__ int sig(int jt, int m) {
    return 32 * (jt >> 1) + 4 * (jt & 1) + 8 * (m >> 2) + (m & 3);
}

__launch_bounds__(512, 2)
__global__ void hmm_fwd_kernel(const float* __restrict__ xg,     // [B][T][S]
                               const float* __restrict__ trans,  // [U][N][N]
                               const float* __restrict__ emis,   // [U][N][S]
                               const float* __restrict__ initk,  // [U][N]
                               float* __restrict__ out)          // [B][T][U]
{
    __shared__ __bf16 AT[N_ * ROWP];
    __shared__ float BemS[N_][S_];
    __shared__ float IS[N_];

    const int bid = blockIdx.x;
    const int u = ((bid & 7) << 5) | (bid >> 3);   // XCD-aware u swizzle
    const int tid = threadIdx.x;
    const int lane = tid & 63;
    const int w = tid >> 6;          // 0..7: batch octet group
    const int q = lane >> 4;
    const int l = lane & 15;
    const bool lval = (l < 8);       // col-valid lane

    // ---------------- prologue: softmaxes (one-time) ----------------
    if (tid < 64) {
        const float* rowp = trans + (u * N_ + tid) * N_;
        float v[N_];
        #pragma unroll
        for (int k = 0; k < 16; ++k) {
            floatx4 t4 = *(const floatx4*)(rowp + 4 * k);
            v[4*k] = t4.x; v[4*k+1] = t4.y; v[4*k+2] = t4.z; v[4*k+3] = t4.w;
        }
        float m = v[0];
        #pragma unroll
        for (int j = 1; j < N_; ++j) m = fmaxf(m, v[j]);
        float s = 0.f;
        #pragma unroll
        for (int j = 0; j < N_; ++j) { v[j] = __expf(v[j] - m); s += v[j]; }
        float inv = 1.0f / s;
        #pragma unroll
        for (int j = 0; j < N_; ++j) AT[j * ROWP + tid] = (__bf16)(v[j] * inv);
    } else if (tid < 128) {
        int n = tid - 64;
        floatx4 e4 = *(const floatx4*)(emis + (u * N_ + n) * S_);
        float m = fmaxf(fmaxf(e4.x, e4.y), fmaxf(e4.z, e4.w));
        float a = __expf(e4.x - m), b2 = __expf(e4.y - m);
        float c = __expf(e4.z - m), d = __expf(e4.w - m);
        float inv = 1.0f / (a + b2 + c + d);
        BemS[n][0] = a*inv; BemS[n][1] = b2*inv; BemS[n][2] = c*inv; BemS[n][3] = d*inv;
    } else if (tid < 192) {
        int j = tid - 128;
        float v = initk[u * N_ + j];
        float m = v;
        #pragma unroll
        for (int s = 1; s < 64; s <<= 1) m = fmaxf(m, __shfl_xor(m, s, 64));
        float e = __expf(v - m);
        float ssum = e;
        #pragma unroll
        for (int s = 1; s < 64; s <<= 1) ssum += __shfl_xor(ssum, s, 64);
        IS[j] = e / ssum;
    }
    __syncthreads();

    // ------------- persistent register state -------------
    bf16x8 afrag[4][2];
    #pragma unroll
    for (int jt = 0; jt < 4; ++jt)
        #pragma unroll
        for (int kt = 0; kt < 2; ++kt)
            afrag[jt][kt] = *(const bf16x8*)&AT[sig(jt, l) * ROWP + 32*kt + 8*q];

    bf16x8 afragE[4];
    #pragma unroll
    for (int jt = 0; jt < 4; ++jt) {
        #pragma unroll
        for (int pp = 0; pp < 8; ++pp) afragE[jt][pp] = (__bf16)0.f;
        if (q == 0) {
            #pragma unroll
            for (int c = 0; c < 4; ++c)
                afragE[jt][c] = (__bf16)BemS[sig(jt, l)][c];
        }
    }

    // Rv(t) = P0+P1 combined lag-1 on VALU (R13, unchained).
    // Lanes l>=8: P0 = 0 -> their R-state stays identically zero forever.
    floatx4 P0[4], P1[4];
    #pragma unroll
    for (int jt = 0; jt < 4; ++jt)
        #pragma unroll
        for (int r = 0; r < 4; ++r) {
            P0[jt][r] = lval ? IS[sig(jt, 4*q + r)] : 0.f;
            P1[jt][r] = 0.f;
        }

    __asm__ volatile("" ::: "memory");   // pin LDS-sourced state in VGPRs

    const int b = 8 * w + (l & 7);
    const float* xin = xg + b * (T_ * S_);
    float* llout = out + (size_t)b * T_ * U_ + u;

    const floatx4 z = {0.f, 0.f, 0.f, 0.f};
    floatx4 Ev[4];

    bf16x8 be;
    #pragma unroll
    for (int pp = 0; pp < 8; ++pp) be[pp] = (__bf16)0.f;   // hi half stays 0

    // ---------------- pipeline fill ----------------
    {
        floatx4 x0 = *(const floatx4*)xin;
        be[0] = (__bf16)x0.x; be[1] = (__bf16)x0.y;
        be[2] = (__bf16)x0.z; be[3] = (__bf16)x0.w;
        #pragma unroll
        for (int jt = 0; jt < 4; ++jt)
            Ev[jt] = __builtin_amdgcn_mfma_f32_16x16x32_bf16(afragE[jt], be, z, 0, 0, 0);
    }
    floatx4 xvA[4], xvB[4];
    #pragma unroll
    for (int i = 0; i < 4; ++i)
        xvA[i] = *(const floatx4*)(xin + (1 + i) * S_);   // x_1..x_4 raw

    float hist[8];
    float ssf = 1.0f;
    float fcur = 1.0f;
    float pp0 = 0.f, pa16 = 0.f, pa32 = 0.f, pa48 = 0.f;
    float Cacc = 0.f;
    float offacc = 0.f, sumk = 0.f;

    // consume step (slot kprev)'s shfl results: raw ss capture only.
    auto consume = [&](int kprev, bool o) {
        float ss = (pp0 + pa16) + (pa32 + pa48);
        hist[kprev] = o ? ss : hist[kprev];
        if (kprev == 5) ssf = ss;
    };

    // one HMM step. xr = raw x_{t+1}; fsc = 1 except slot 0 (octet rescale).
    auto step = [&](const floatx4& xr, int slot, bool own, bool ownP, float fsc) {
        // ---------- V phase ----------
        floatx4 gv[4];
        #pragma unroll
        for (int jt = 0; jt < 4; ++jt) {
            floatx4 Rv = P0[jt] + P1[jt];
            gv[jt] = (Ev[jt] * Rv) * fsc;
        }

        bf16x8 bf0, bf1;
        #pragma unroll
        for (int pp = 0; pp < 4; ++pp) {
            bf0[pp]     = (__bf16)gv[0][pp];
            bf0[4 + pp] = (__bf16)gv[1][pp];
            bf1[pp]     = (__bf16)gv[2][pp];
            bf1[4 + pp] = (__bf16)gv[3][pp];
        }

        // be: only low 4 elems change (hi half constant zero)
        be[0] = (__bf16)xr.x; be[1] = (__bf16)xr.y;
        be[2] = (__bf16)xr.z; be[3] = (__bf16)xr.w;

        // ---------- M phase: 12 mutually independent MFMAs ----------
        #pragma unroll
        for (int jt = 0; jt < 4; ++jt)
            P0[jt] = __builtin_amdgcn_mfma_f32_16x16x32_bf16(afrag[jt][0], bf0, z, 0, 0, 0);
        #pragma unroll
        for (int jt = 0; jt < 4; ++jt)
            P1[jt] = __builtin_amdgcn_mfma_f32_16x16x32_bf16(afrag[jt][1], bf1, z, 0, 0, 0);

        // consume previous step's shfl results (issued ~1 step ago)
        if (slot == 0) consume(7, ownP); else consume(slot - 1, own);

        #pragma unroll
        for (int jt = 0; jt < 4; ++jt)
            Ev[jt] = __builtin_amdgcn_mfma_f32_16x16x32_bf16(afragE[jt], be, z, 0, 0, 0);

        // ss reduce issued last, consumed lag-1
        floatx4 s4 = (gv[0] + gv[1]) + (gv[2] + gv[3]);
        pp0  = (s4.x + s4.y) + (s4.z + s4.w);
        pa16 = __shfl_xor(pp0, 16, 64);
        pa32 = __shfl_xor(pp0, 32, 64);
        pa48 = __shfl_xor(pp0, 48, 64);
    };

    // ---------------- T-loop: one octet per iteration ----------------
    #pragma unroll 1
    for (int tb = 0; tb < T_; tb += 8) {
        const int oct = (tb >> 3) & 3;
        const bool own  = (q == oct);
        const bool ownP = (q == ((oct + 3) & 3));

        #pragma unroll
        for (int i = 0; i < 4; ++i) {
            int ti = tb + 5 + i; ti = (ti < T_) ? ti : T_ - 1;
            xvB[i] = *(const floatx4*)(xin + ti * S_);
        }

        step(xvA[0], 0, own, ownP, fcur);
        step(xvA[1], 1, own, ownP, 1.0f);
        step(xvA[2], 2, own, ownP, 1.0f);
        step(xvA[3], 3, own, ownP, 1.0f);

        #pragma unroll
        for (int i = 0; i < 4; ++i) {
            int ti = tb + 9 + i; ti = (ti < T_) ? ti : T_ - 1;
            xvA[i] = *(const floatx4*)(xin + ti * S_);
        }

        step(xvB[0], 4, own, ownP, 1.0f);
        step(xvB[1], 5, own, ownP, 1.0f);
        step(xvB[2], 6, own, ownP, 1.0f);
        step(xvB[3], 7, own, ownP, 1.0f);

        if (oct == 3) consume(7, own);   // pre-flush tail (once per 32)

        // octet boundary: derive next pow2 rescale from ssraw_{slot5};
        // applied at next octet's slot 0 via gv *= fcur.
        {
            unsigned eb = (__float_as_uint(ssf) >> 23) & 255u;
            fcur = __uint_as_float((254u - eb) << 23);
            float kf = (float)((int)eb - 127);
            offacc += (q > oct) ? kf : 0.f;   // octets before lane q's octet
            sumk   += kf;
        }

        // ---------------- flush: ll_t = log(ssraw_t) + correction -------
        if (oct == 3) {
            float base = Cacc + LN2F * offacc;
            if (lval) {
                float* fp = llout + (size_t)(tb - 24 + 8 * q) * U_;
                #pragma unroll
                for (int k = 0; k < 8; ++k)
                    fp[(size_t)k * U_] = __logf(hist[k]) + base;
            }
            Cacc += LN2F * sumk;
            offacc = 0.f; sumk = 0.f;
        }
    }
}

extern "C" void kernel_launch(void* const* d_in, const int* in_sizes, int n_in,
                              void* d_out, int out_size, void* d_ws, size_t ws_size,
                              hipStream_t stream) {
    const float* xg    = (const float*)d_in[0];
    const float* trans = (const float*)d_in[1];
    const float* emis  = (const float*)d_in[2];
    const float* initk = (const float*)d_in[3];
    float* out = (float*)d_out;
    hipLaunchKernelGGL(hmm_fwd_kernel, dim3(U_), dim3(512), 0, stream,
                       xg, trans, emis, initk, out);
}

// Round 9
// 325.745 us; speedup vs baseline: 1.4947x; 1.4510x over previous
//
#include <hip/hip_runtime.h>

// HMM forward scan, one workgroup per unit u. U=256, N=64, S=4, B=64, T=1024.
// Wave w owns batches [16w,16w+16); lane (q=lane>>4,l=lane&15) owns batch
// b=16w+l and the 16 states j = sig(jt, 4q+r).
//
// R17 = R13 + dependency-slack surgery. Evidence: R16 showed per-SIMD
// issue throughput RISES with 2 waves but no decomposition adds waves
// without adding work -> optimize R13's per-wave step (732cy = 246 MFMA
// + ~210 VALU + ~270 stall). The least-covered operand in R13 is Ev:
// E-MFMAs issue LAST in M(t), read ~30cy into V(t+1) -> exposed MFMA
// latency every step. Fixes:
//  - LAG-2 E: step t's M-phase computes E_{t+2} (x_{t+2} prefetched);
//    EvA/EvB ping-pong by slot parity (static names). Ev cover 30->~700cy.
//  - V-phase reads ordered oldest-first: consume(ss, cover 70+), then
//    Rv=P0+P1 (cover 105+), then gv (Ev lag-2).
//  - Rescale mul only at slot 0 (compile-time folded) - R13 paid 16
//    muls/step on fsc=1.0 for 7/8 steps.
// Bit-identical math to R13 (same MFMAs, same operand values; x1.0 mul
// removed). Unnormalized recursion + exact pow2 octet rescale +
// once-per-32 flush unchanged (proven R10/R13).

#define U_ 256
#define N_ 64
#define S_ 4
#define B_ 64
#define T_ 1024
#define ROWP 72
#define LN2F 0.69314718055994530942f

typedef __attribute__((ext_vector_type(8))) __bf16 bf16x8;
typedef __attribute__((ext_vector_type(4))) float floatx4;

__device__ __forceinline__ int sig(int jt, int m) {
    return 32 * (jt >> 1) + 4 * (jt & 1) + 8 * (m >> 2) + (m & 3);
}

__launch_bounds__(256, 1)
__global__ void hmm_fwd_kernel(const float* __restrict__ xg,     // [B][T][S]
                               const float* __restrict__ trans,  // [U][N][N]
                               const float* __restrict__ emis,   // [U][N][S]
                               const float* __restrict__ initk,  // [U][N]
                               float* __restrict__ out)          // [B][T][U]
{
    __shared__ __bf16 AT[N_ * ROWP];
    __shared__ float BemS[N_][S_];
    __shared__ float IS[N_];

    const int bid = blockIdx.x;
    const int u = ((bid & 7) << 5) | (bid >> 3);   // XCD-aware u swizzle
    const int tid = threadIdx.x;
    const int lane = tid & 63;
    const int w = tid >> 6;
    const int q = lane >> 4;
    const int l = lane & 15;

    // ---------------- prologue: softmaxes (one-time) ----------------
    if (tid < 64) {
        const float* rowp = trans + (u * N_ + tid) * N_;
        float v[N_];
        #pragma unroll
        for (int k = 0; k < 16; ++k) {
            floatx4 t4 = *(const floatx4*)(rowp + 4 * k);
            v[4*k] = t4.x; v[4*k+1] = t4.y; v[4*k+2] = t4.z; v[4*k+3] = t4.w;
        }
        float m = v[0];
        #pragma unroll
        for (int j = 1; j < N_; ++j) m = fmaxf(m, v[j]);
        float s = 0.f;
        #pragma unroll
        for (int j = 0; j < N_; ++j) { v[j] = __expf(v[j] - m); s += v[j]; }
        float inv = 1.0f / s;
        #pragma unroll
        for (int j = 0; j < N_; ++j) AT[j * ROWP + tid] = (__bf16)(v[j] * inv);
    } else if (tid < 128) {
        int n = tid - 64;
        floatx4 e4 = *(const floatx4*)(emis + (u * N_ + n) * S_);
        float m = fmaxf(fmaxf(e4.x, e4.y), fmaxf(e4.z, e4.w));
        float a = __expf(e4.x - m), b2 = __expf(e4.y - m);
        float c = __expf(e4.z - m), d = __expf(e4.w - m);
        float inv = 1.0f / (a + b2 + c + d);
        BemS[n][0] = a*inv; BemS[n][1] = b2*inv; BemS[n][2] = c*inv; BemS[n][3] = d*inv;
    } else if (tid < 192) {
        int j = tid - 128;
        float v = initk[u * N_ + j];
        float m = v;
        #pragma unroll
        for (int s = 1; s < 64; s <<= 1) m = fmaxf(m, __shfl_xor(m, s, 64));
        float e = __expf(v - m);
        float ssum = e;
        #pragma unroll
        for (int s = 1; s < 64; s <<= 1) ssum += __shfl_xor(ssum, s, 64);
        IS[j] = e / ssum;
    }
    __syncthreads();

    // ------------- persistent register state -------------
    bf16x8 afrag[4][2];
    #pragma unroll
    for (int jt = 0; jt < 4; ++jt)
        #pragma unroll
        for (int kt = 0; kt < 2; ++kt)
            afrag[jt][kt] = *(const bf16x8*)&AT[sig(jt, l) * ROWP + 32*kt + 8*q];

    bf16x8 afragE[4];
    #pragma unroll
    for (int jt = 0; jt < 4; ++jt) {
        #pragma unroll
        for (int pp = 0; pp < 8; ++pp) afragE[jt][pp] = (__bf16)0.f;
        if (q == 0) {
            #pragma unroll
            for (int c = 0; c < 4; ++c)
                afragE[jt][c] = (__bf16)BemS[sig(jt, l)][c];
        }
    }

    bf16x8 onesf;
    #pragma unroll
    for (int pp = 0; pp < 8; ++pp) onesf[pp] = (__bf16)1.0f;

    // Rv(t) = P0+P1 combined lag-1 on VALU (R13, unchained)
    floatx4 P0[4], P1[4];
    #pragma unroll
    for (int jt = 0; jt < 4; ++jt)
        #pragma unroll
        for (int r = 0; r < 4; ++r) {
            P0[jt][r] = IS[sig(jt, 4*q + r)];
            P1[jt][r] = 0.f;
        }

    __asm__ volatile("" ::: "memory");   // pin LDS-sourced state in VGPRs

    const int b = 16*w + l;
    const float* xin = xg + b * (T_ * S_);
    float* llout = out + (size_t)b * T_ * U_ + u;

    const floatx4 z = {0.f, 0.f, 0.f, 0.f};
    floatx4 ssvA = z, ssvB = z;          // prev step's ones-MFMA half-sums

    bf16x8 be;
    #pragma unroll
    for (int pp = 0; pp < 8; ++pp) be[pp] = (__bf16)0.f;   // hi half stays 0

    // E ping-pong buffers: EvA = even slots, EvB = odd slots (lag-2 fill)
    floatx4 EvA[4], EvB[4];

    // ---------------- pipeline fill: E_0 and E_1 ----------------
    {
        floatx4 x0 = *(const floatx4*)xin;
        be[0] = (__bf16)x0.x; be[1] = (__bf16)x0.y;
        be[2] = (__bf16)x0.z; be[3] = (__bf16)x0.w;
        #pragma unroll
        for (int jt = 0; jt < 4; ++jt)
            EvA[jt] = __builtin_amdgcn_mfma_f32_16x16x32_bf16(afragE[jt], be, z, 0, 0, 0);
    }
    floatx4 xvA[4], xvB[4];
    #pragma unroll
    for (int i = 0; i < 4; ++i)
        xvA[i] = *(const floatx4*)(xin + (1 + i) * S_);   // x_1..x_4 raw
    {
        floatx4 x1 = xvA[0];
        be[0] = (__bf16)x1.x; be[1] = (__bf16)x1.y;
        be[2] = (__bf16)x1.z; be[3] = (__bf16)x1.w;
        #pragma unroll
        for (int jt = 0; jt < 4; ++jt)
            EvB[jt] = __builtin_amdgcn_mfma_f32_16x16x32_bf16(afragE[jt], be, z, 0, 0, 0);
    }

    float hist[8];
    float ssf = 1.0f;
    float fcur = 1.0f;
    float Cacc = 0.f;
    float offacc = 0.f, sumk = 0.f;

    // one HMM step. xr2 = raw x_{t+2}; Ein = E_t (read), Eout = E_{t+2}
    // (written; same buffer as Ein — read-before-write). slot is a literal
    // at every call site -> all slot branches constant-fold.
    auto step = [&](const floatx4& xr2, int slot, bool own, bool ownP,
                    const floatx4* Ein, floatx4* Eout) {
        // ---------- V phase (reads ordered oldest-first) ----------
        // 1) consume prev step's ss (issued mid prev-M, cover ~70cy+)
        {
            float ssp = ssvA[0] + ssvB[0];
            if (slot == 0) {
                hist[7] = ownP ? ssp : hist[7];
            } else {
                hist[slot - 1] = own ? ssp : hist[slot - 1];
                if (slot == 6) ssf = ssp;   // slot-5 ss, 2 steps of slack
            }
        }

        // 2) Rv = P0+P1 (prev-M R-MFMAs, cover ~105cy+), gv = Ev o Rv
        floatx4 gv[4];
        #pragma unroll
        for (int jt = 0; jt < 4; ++jt) {
            floatx4 Rv = P0[jt] + P1[jt];
            gv[jt] = Ein[jt] * Rv;       // Ev lag-2: cover ~1 full step
        }
        if (slot == 0) {                 // octet pow2 rescale (folded only here)
            #pragma unroll
            for (int jt = 0; jt < 4; ++jt) gv[jt] *= fcur;
        }

        // 3) packs
        bf16x8 bf0, bf1;
        #pragma unroll
        for (int pp = 0; pp < 4; ++pp) {
            bf0[pp]     = (__bf16)gv[0][pp];
            bf0[4 + pp] = (__bf16)gv[1][pp];
            bf1[pp]     = (__bf16)gv[2][pp];
            bf1[4 + pp] = (__bf16)gv[3][pp];
        }
        be[0] = (__bf16)xr2.x; be[1] = (__bf16)xr2.y;
        be[2] = (__bf16)xr2.z; be[3] = (__bf16)xr2.w;

        // ---------- M phase: 14 mutually independent MFMAs ----------
        #pragma unroll
        for (int jt = 0; jt < 4; ++jt)
            P0[jt] = __builtin_amdgcn_mfma_f32_16x16x32_bf16(afrag[jt][0], bf0, z, 0, 0, 0);
        #pragma unroll
        for (int jt = 0; jt < 4; ++jt)
            P1[jt] = __builtin_amdgcn_mfma_f32_16x16x32_bf16(afrag[jt][1], bf1, z, 0, 0, 0);
        ssvA = __builtin_amdgcn_mfma_f32_16x16x32_bf16(onesf, bf0, z, 0, 0, 0);
        ssvB = __builtin_amdgcn_mfma_f32_16x16x32_bf16(onesf, bf1, z, 0, 0, 0);
        #pragma unroll
        for (int jt = 0; jt < 4; ++jt)
            Eout[jt] = __builtin_amdgcn_mfma_f32_16x16x32_bf16(afragE[jt], be, z, 0, 0, 0);
    };

    // ---------------- T-loop: one octet per iteration ----------------
    #pragma unroll 1
    for (int tb = 0; tb < T_; tb += 8) {
        const int oct = (tb >> 3) & 3;
        const bool own  = (q == oct);
        const bool ownP = (q == ((oct + 3) & 3));

        #pragma unroll
        for (int i = 0; i < 4; ++i) {
            int ti = tb + 5 + i; ti = (ti < T_) ? ti : T_ - 1;
            xvB[i] = *(const floatx4*)(xin + ti * S_);
        }

        // slot s consumes x_{tb+s+2} for its lag-2 E
        step(xvA[1], 0, own, ownP, EvA, EvA);
        step(xvA[2], 1, own, ownP, EvB, EvB);
        step(xvA[3], 2, own, ownP, EvA, EvA);
        step(xvB[0], 3, own, ownP, EvB, EvB);

        #pragma unroll
        for (int i = 0; i < 4; ++i) {
            int ti = tb + 9 + i; ti = (ti < T_) ? ti : T_ - 1;
            xvA[i] = *(const floatx4*)(xin + ti * S_);
        }

        step(xvB[1], 4, own, ownP, EvA, EvA);
        step(xvB[2], 5, own, ownP, EvB, EvB);
        step(xvB[3], 6, own, ownP, EvA, EvA);
        step(xvA[0], 7, own, ownP, EvB, EvB);

        if (oct == 3) {   // pre-flush tail capture of slot 7 (once per 32)
            float ssp = ssvA[0] + ssvB[0];
            hist[7] = own ? ssp : hist[7];
        }

        // octet boundary: derive next pow2 rescale from ssraw_{slot5};
        // applied at next octet's slot 0 via gv *= fcur.
        {
            unsigned eb = (__float_as_uint(ssf) >> 23) & 255u;
            fcur = __uint_as_float((254u - eb) << 23);
            float kf = (float)((int)eb - 127);
            offacc += (q > oct) ? kf : 0.f;   // octets before lane q's octet
            sumk   += kf;
        }

        // ---------------- flush: ll_t = log(ssraw_t) + correction -------
        if (oct == 3) {
            float base = Cacc + LN2F * offacc;
            float* fp = llout + (size_t)(tb - 24 + 8 * q) * U_;
            #pragma unroll
            for (int k = 0; k < 8; ++k)
                fp[(size_t)k * U_] = __logf(hist[k]) + base;
            Cacc += LN2F * sumk;
            offacc = 0.f; sumk = 0.f;
        }
    }
}

extern "C" void kernel_launch(void* const* d_in, const int* in_sizes, int n_in,
                              void* d_out, int out_size, void* d_ws, size_t ws_size,
                              hipStream_t stream) {
    const float* xg    = (const float*)d_in[0];
    const float* trans = (const float*)d_in[1];
    const float* emis  = (const float*)d_in[2];
    const float* initk = (const float*)d_in[3];
    float* out = (float*)d_out;
    hipLaunchKernelGGL(hmm_fwd_kernel, dim3(U_), dim3(256), 0, stream,
                       xg, trans, emis, initk, out);
}